// Round 11
// baseline (69.154 us; speedup 1.0000x reference)
//
#include <hip/hip_runtime.h>

// b=4, f=6, n_slots=7, n_buffer=8, h=w=128, 3 channels. bf=24.
constexpr int NB  = 8;
constexpr int NS  = 7;
constexpr int NCH = 3;
constexpr int HW  = 128 * 128;    // 16384
constexpr int HW2 = HW / 2;       // float2 per plane
constexpr int BF  = 24;
constexpr int BLOCK = 256;
constexpr int PXCHUNKS = HW / (BLOCK * 2);       // 32 px-chunks (512 px each)
constexpr int BLOCKS_PER_BF = PXCHUNKS * 2;      // 64 (x2 c-halves)
constexpr int NPART = BF * BLOCKS_PER_BF;        // 1536 blocks / partials
constexpr float INV_HW = 1.0f / (float)HW;
constexpr float SCALE  = 20.0f / (4.0f * 6.0f * 7.0f * 8.0f);
constexpr float LOG_CLAMP = -100.0f;

__global__ __launch_bounds__(BLOCK, 4)   // VGPR cap 128
void em_loss_kernel(const float* __restrict__ seg,
                    const float* __restrict__ masks,
                    const float* __restrict__ rec,
                    const float* __restrict__ rtgt,
                    const float* __restrict__ mvis,
                    const float* __restrict__ ai,
                    float* __restrict__ part,
                    unsigned* __restrict__ counter,
                    float* __restrict__ out) {
    const int bid  = blockIdx.x;
    const int bf   = bid >> 6;                   // / BLOCKS_PER_BF
    const int rem  = bid & 63;
    // bit3 = c-half: blocks sharing a px-chunk are 8 apart -> same XCD under
    // round-robin dispatch -> L2 dedups the shared masks/mvis/rtgt reads.
    const int half  = (rem >> 3) & 1;
    const int chunk = (rem & 7) | ((rem >> 4) << 3);   // 0..31
    const int tid   = threadIdx.x;
    const int v2    = chunk * BLOCK + tid;       // float2 index in plane
    const int c0    = half * 4;

    __shared__ float ai_s[NS][NB];
    __shared__ float A_s[NB];
    if (tid < NS * NB)
        ((float*)ai_s)[tid] = ai[bf * NS * NB + tid];
    __syncthreads();
    if (tid < NB) {
        float a = 0.f;
        #pragma unroll
        for (int s = 0; s < NS; ++s) a += ai_s[s][tid];
        A_s[tid] = a;
    }
    __syncthreads();

    const float2* segp = (const float2*)(seg  + (size_t)bf * NB * HW)       + v2;
    const float2* mp   = (const float2*)(masks + (size_t)bf * NS * HW)      + v2;
    const float2* rp   = (const float2*)(rec  + (size_t)bf * NB * NCH * HW) + v2;
    const float2* tp   = (const float2*)(rtgt + (size_t)bf * NCH * HW)      + v2;
    const float2* vp   = (const float2*)(mvis + (size_t)bf * NS * HW)       + v2;

    // ---- Issue ALL 33 float2 loads; sched_barrier pins them as one cluster ----
    float2 mv[NS], vv[NS];
    #pragma unroll
    for (int s = 0; s < NS; ++s) mv[s] = mp[s * HW2];
    #pragma unroll
    for (int s = 0; s < NS; ++s) vv[s] = vp[s * HW2];

    float2 tv[NCH];
    #pragma unroll
    for (int ch = 0; ch < NCH; ++ch) tv[ch] = tp[ch * HW2];

    float2 sv[4];
    #pragma unroll
    for (int c4 = 0; c4 < 4; ++c4) sv[c4] = segp[(c0 + c4) * HW2];

    float2 rr[4][NCH];
    #pragma unroll
    for (int c4 = 0; c4 < 4; ++c4)
        #pragma unroll
        for (int ch = 0; ch < NCH; ++ch)
            rr[c4][ch] = rp[((c0 + c4) * NCH + ch) * HW2];

    // Nothing may cross: forces all 33 load results simultaneously live
    // (66 VGPRs), preventing the R10 register-reuse collapse to serial loads.
    __builtin_amdgcn_sched_barrier(0);

    // ---- Compute ----
    float mb[NS][2], vb[NS][2];
    #pragma unroll
    for (int s = 0; s < NS; ++s) {
        mb[s][0] = (mv[s].x > 0.5f) ? 1.f : 0.f;
        mb[s][1] = (mv[s].y > 0.5f) ? 1.f : 0.f;
        vb[s][0] = (vv[s].x > 0.5f) ? 1.f : 0.f;
        vb[s][1] = (vv[s].y > 0.5f) ? 1.f : 0.f;
    }

    float acc = 0.f;
    #pragma unroll
    for (int c4 = 0; c4 < 4; ++c4) {
        const int c = c0 + c4;
        const float Ac = A_s[c];
        const float* sp  = (const float*)&sv[c4];
        const float* r0p = (const float*)&rr[c4][0];
        const float* r1p = (const float*)&rr[c4][1];
        const float* r2p = (const float*)&rr[c4][2];
        const float* t0p = (const float*)&tv[0];
        const float* t1p = (const float*)&tv[1];
        const float* t2p = (const float*)&tv[2];
        #pragma unroll
        for (int j = 0; j < 2; ++j) {
            float s  = sp[j];
            float lp = fmaxf(__logf(s), LOG_CLAMP);
            float l1 = fmaxf(__logf(1.0f - s), LOG_CLAMP);
            float d0 = r0p[j] - t0p[j];
            float d1 = r1p[j] - t1p[j];
            float d2 = r2p[j] - t2p[j];
            float D  = d0 * d0 + d1 * d1 + d2 * d2;
            float U = 0.f, V = 0.f;
            #pragma unroll
            for (int s7 = 0; s7 < NS; ++s7) {
                float a = ai_s[s7][c];
                U = fmaf(mb[s7][j], a, U);
                V = fmaf(vb[s7][j], a, V);
            }
            acc += -(Ac * l1 + U * (lp - l1)) * INV_HW + 0.1f * V * D;
        }
    }

    // wave reduce, cross-wave via LDS
    #pragma unroll
    for (int off = 32; off; off >>= 1) acc += __shfl_down(acc, off, 64);
    __shared__ float wsum[BLOCK / 64];
    const int wid  = tid >> 6;
    const int lane = tid & 63;
    if (lane == 0) wsum[wid] = acc;
    __syncthreads();

    // ---- fused final reduction: last block to finish sums all partials ----
    __shared__ bool last;
    if (tid == 0) {
        part[bid] = wsum[0] + wsum[1] + wsum[2] + wsum[3];
        __threadfence();                          // publish partial before count
        last = (atomicAdd(counter, 1u) == NPART - 1);
    }
    __syncthreads();
    if (last) {
        __threadfence();                          // acquire all partials
        float a = 0.f;
        #pragma unroll
        for (int i = 0; i < NPART / BLOCK; ++i)   // 6 each
            a += part[i * BLOCK + tid];
        #pragma unroll
        for (int off = 32; off; off >>= 1) a += __shfl_down(a, off, 64);
        if (lane == 0) wsum[wid] = a;
        __syncthreads();
        if (tid == 0)
            out[0] = (wsum[0] + wsum[1] + wsum[2] + wsum[3]) * SCALE;
    }
}

extern "C" void kernel_launch(void* const* d_in, const int* in_sizes, int n_in,
                              void* d_out, int out_size, void* d_ws, size_t ws_size,
                              hipStream_t stream) {
    const float* seg   = (const float*)d_in[0];  // (4,6,8,128,128)
    const float* masks = (const float*)d_in[1];  // (4,6,7,128,128)
    const float* rec   = (const float*)d_in[2];  // (4,6,8,3,128,128)
    const float* rtgt  = (const float*)d_in[3];  // (4,6,3,128,128)
    const float* mvis  = (const float*)d_in[4];  // (4,6,7,128,128)
    const float* ai    = (const float*)d_in[5];  // (4,6,7,8)
    float* out  = (float*)d_out;
    float* part = (float*)d_ws;                  // NPART floats + 1 uint counter
    unsigned* counter = (unsigned*)(part + NPART);

    hipMemsetAsync(counter, 0, sizeof(unsigned), stream);
    em_loss_kernel<<<NPART, BLOCK, 0, stream>>>(seg, masks, rec, rtgt, mvis, ai,
                                                part, counter, out);
}

// Round 12
// 67.957 us; speedup vs baseline: 1.0176x; 1.0176x over previous
//
#include <hip/hip_runtime.h>

// b=4, f=6, n_slots=7, n_buffer=8, h=w=128, 3 channels. bf=24.
constexpr int NB  = 8;
constexpr int NS  = 7;
constexpr int NCH = 3;
constexpr int HW  = 128 * 128;    // 16384
constexpr int HW2 = HW / 2;       // float2 per plane
constexpr int BF  = 24;
constexpr int BLOCK = 256;
constexpr int PXCHUNKS = HW / (BLOCK * 2);       // 32 px-chunks (512 px each)
constexpr int BLOCKS_PER_BF = PXCHUNKS * 2;      // 64 (x2 c-halves)
constexpr int NPART = BF * BLOCKS_PER_BF;        // 1536 blocks / partials
constexpr float INV_HW = 1.0f / (float)HW;
constexpr float SCALE  = 20.0f / (4.0f * 6.0f * 7.0f * 8.0f);
constexpr float LOG_CLAMP = -100.0f;

// waves_per_eu(4,4): pin the backend's occupancy target to exactly 4 waves/EU
// so the allocator optimizes ILP at <=128 VGPR instead of squeezing to 48 and
// serializing the load cluster (the R3/R9/R10/R11 failure mode).
__global__
__attribute__((amdgpu_flat_work_group_size(256, 256), amdgpu_waves_per_eu(4, 4)))
void em_loss_kernel(const float* __restrict__ seg,
                    const float* __restrict__ masks,
                    const float* __restrict__ rec,
                    const float* __restrict__ rtgt,
                    const float* __restrict__ mvis,
                    const float* __restrict__ ai,
                    float* __restrict__ part,
                    unsigned* __restrict__ counter,
                    float* __restrict__ out) {
    const int bid  = blockIdx.x;
    const int bf   = bid >> 6;                   // / BLOCKS_PER_BF
    const int rem  = bid & 63;
    // bit3 = c-half: blocks sharing a px-chunk are 8 apart -> same XCD under
    // round-robin dispatch -> L2 dedups the shared masks/mvis/rtgt reads.
    const int half  = (rem >> 3) & 1;
    const int chunk = (rem & 7) | ((rem >> 4) << 3);   // 0..31
    const int tid   = threadIdx.x;
    const int v2    = chunk * BLOCK + tid;       // float2 index in plane
    const int c0    = half * 4;

    __shared__ float ai_s[NS][NB];
    __shared__ float A_s[NB];
    if (tid < NS * NB)
        ((float*)ai_s)[tid] = ai[bf * NS * NB + tid];
    __syncthreads();
    if (tid < NB) {
        float a = 0.f;
        #pragma unroll
        for (int s = 0; s < NS; ++s) a += ai_s[s][tid];
        A_s[tid] = a;
    }
    __syncthreads();

    const float2* segp = (const float2*)(seg  + (size_t)bf * NB * HW)       + v2;
    const float2* mp   = (const float2*)(masks + (size_t)bf * NS * HW)      + v2;
    const float2* rp   = (const float2*)(rec  + (size_t)bf * NB * NCH * HW) + v2;
    const float2* tp   = (const float2*)(rtgt + (size_t)bf * NCH * HW)      + v2;
    const float2* vp   = (const float2*)(mvis + (size_t)bf * NS * HW)       + v2;

    // ---- Issue ALL 33 float2 loads as one cluster ----
    float2 mv[NS], vv[NS];
    #pragma unroll
    for (int s = 0; s < NS; ++s) mv[s] = mp[s * HW2];
    #pragma unroll
    for (int s = 0; s < NS; ++s) vv[s] = vp[s * HW2];

    float2 tv[NCH];
    #pragma unroll
    for (int ch = 0; ch < NCH; ++ch) tv[ch] = tp[ch * HW2];

    float2 sv[4];
    #pragma unroll
    for (int c4 = 0; c4 < 4; ++c4) sv[c4] = segp[(c0 + c4) * HW2];

    float2 rr[4][NCH];
    #pragma unroll
    for (int c4 = 0; c4 < 4; ++c4)
        #pragma unroll
        for (int ch = 0; ch < NCH; ++ch)
            rr[c4][ch] = rp[((c0 + c4) * NCH + ch) * HW2];

    __builtin_amdgcn_sched_barrier(0);

    // ---- Compute ----
    float mb[NS][2], vb[NS][2];
    #pragma unroll
    for (int s = 0; s < NS; ++s) {
        mb[s][0] = (mv[s].x > 0.5f) ? 1.f : 0.f;
        mb[s][1] = (mv[s].y > 0.5f) ? 1.f : 0.f;
        vb[s][0] = (vv[s].x > 0.5f) ? 1.f : 0.f;
        vb[s][1] = (vv[s].y > 0.5f) ? 1.f : 0.f;
    }

    float acc = 0.f;
    #pragma unroll
    for (int c4 = 0; c4 < 4; ++c4) {
        const int c = c0 + c4;
        const float Ac = A_s[c];
        const float* sp  = (const float*)&sv[c4];
        const float* r0p = (const float*)&rr[c4][0];
        const float* r1p = (const float*)&rr[c4][1];
        const float* r2p = (const float*)&rr[c4][2];
        const float* t0p = (const float*)&tv[0];
        const float* t1p = (const float*)&tv[1];
        const float* t2p = (const float*)&tv[2];
        #pragma unroll
        for (int j = 0; j < 2; ++j) {
            float s  = sp[j];
            float lp = fmaxf(__logf(s), LOG_CLAMP);
            float l1 = fmaxf(__logf(1.0f - s), LOG_CLAMP);
            float d0 = r0p[j] - t0p[j];
            float d1 = r1p[j] - t1p[j];
            float d2 = r2p[j] - t2p[j];
            float D  = d0 * d0 + d1 * d1 + d2 * d2;
            float U = 0.f, V = 0.f;
            #pragma unroll
            for (int s7 = 0; s7 < NS; ++s7) {
                float a = ai_s[s7][c];
                U = fmaf(mb[s7][j], a, U);
                V = fmaf(vb[s7][j], a, V);
            }
            acc += -(Ac * l1 + U * (lp - l1)) * INV_HW + 0.1f * V * D;
        }
    }

    // wave reduce, cross-wave via LDS
    #pragma unroll
    for (int off = 32; off; off >>= 1) acc += __shfl_down(acc, off, 64);
    __shared__ float wsum[BLOCK / 64];
    const int wid  = tid >> 6;
    const int lane = tid & 63;
    if (lane == 0) wsum[wid] = acc;
    __syncthreads();

    // ---- fused final reduction: last block to finish sums all partials ----
    __shared__ bool last;
    if (tid == 0) {
        part[bid] = wsum[0] + wsum[1] + wsum[2] + wsum[3];
        __threadfence();                          // publish partial before count
        last = (atomicAdd(counter, 1u) == NPART - 1);
    }
    __syncthreads();
    if (last) {
        __threadfence();                          // acquire all partials
        float a = 0.f;
        #pragma unroll
        for (int i = 0; i < NPART / BLOCK; ++i)   // 6 each
            a += part[i * BLOCK + tid];
        #pragma unroll
        for (int off = 32; off; off >>= 1) a += __shfl_down(a, off, 64);
        if (lane == 0) wsum[wid] = a;
        __syncthreads();
        if (tid == 0)
            out[0] = (wsum[0] + wsum[1] + wsum[2] + wsum[3]) * SCALE;
    }
}

extern "C" void kernel_launch(void* const* d_in, const int* in_sizes, int n_in,
                              void* d_out, int out_size, void* d_ws, size_t ws_size,
                              hipStream_t stream) {
    const float* seg   = (const float*)d_in[0];  // (4,6,8,128,128)
    const float* masks = (const float*)d_in[1];  // (4,6,7,128,128)
    const float* rec   = (const float*)d_in[2];  // (4,6,8,3,128,128)
    const float* rtgt  = (const float*)d_in[3];  // (4,6,3,128,128)
    const float* mvis  = (const float*)d_in[4];  // (4,6,7,128,128)
    const float* ai    = (const float*)d_in[5];  // (4,6,7,8)
    float* out  = (float*)d_out;
    float* part = (float*)d_ws;                  // NPART floats + 1 uint counter
    unsigned* counter = (unsigned*)(part + NPART);

    hipMemsetAsync(counter, 0, sizeof(unsigned), stream);
    em_loss_kernel<<<NPART, BLOCK, 0, stream>>>(seg, masks, rec, rtgt, mvis, ai,
                                                part, counter, out);
}

// Round 13
// 20.399 us; speedup vs baseline: 3.3901x; 3.3315x over previous
//
#include <hip/hip_runtime.h>

// b=4, f=6, n_slots=7, n_buffer=8, h=w=128, 3 channels. bf=24.
constexpr int NB  = 8;
constexpr int NS  = 7;
constexpr int NCH = 3;
constexpr int HW  = 128 * 128;    // 16384
constexpr int HW2 = HW / 2;       // float2 per plane
constexpr int BF  = 24;
constexpr int BLOCK = 256;
constexpr int PXCHUNKS = HW / (BLOCK * 2);       // 32 px-chunks (512 px each)
constexpr int BLOCKS_PER_BF = PXCHUNKS * 2;      // 64 (x2 c-halves)
constexpr int NPART = BF * BLOCKS_PER_BF;        // 1536 blocks / partials
constexpr float INV_HW = 1.0f / (float)HW;
constexpr float SCALE  = 20.0f / (4.0f * 6.0f * 7.0f * 8.0f);
constexpr float LOG_CLAMP = -100.0f;

typedef float v2f __attribute__((ext_vector_type(2)));

__global__ __launch_bounds__(BLOCK, 4)   // VGPR cap 128: ~110 live, NO spill (R8-proven)
void em_loss_kernel(const float* __restrict__ seg,
                    const float* __restrict__ masks,
                    const float* __restrict__ rec,
                    const float* __restrict__ rtgt,
                    const float* __restrict__ mvis,
                    const float* __restrict__ ai,
                    float* __restrict__ part) {
    const int bid  = blockIdx.x;
    const int bf   = bid >> 6;                   // / BLOCKS_PER_BF
    const int rem  = bid & 63;
    // bit3 = c-half so the two blocks sharing a px-chunk are 8 apart in
    // blockIdx -> same XCD under round-robin dispatch -> L2 dedups shared reads.
    const int half  = (rem >> 3) & 1;
    const int chunk = (rem & 7) | ((rem >> 4) << 3);   // 0..31
    const int tid   = threadIdx.x;
    const int v2    = chunk * BLOCK + tid;       // float2 index in plane
    const int c0    = half * 4;

    __shared__ float ai_s[NS][NB];
    __shared__ float A_s[NB];
    if (tid < NS * NB)
        ((float*)ai_s)[tid] = ai[bf * NS * NB + tid];
    __syncthreads();
    if (tid < NB) {
        float a = 0.f;
        #pragma unroll
        for (int s = 0; s < NS; ++s) a += ai_s[s][tid];
        A_s[tid] = a;
    }
    __syncthreads();

    const v2f* segp = (const v2f*)(seg  + (size_t)bf * NB * HW)       + v2;
    const v2f* mp   = (const v2f*)(masks + (size_t)bf * NS * HW)      + v2;
    const v2f* rp   = (const v2f*)(rec  + (size_t)bf * NB * NCH * HW) + v2;
    const v2f* tp   = (const v2f*)(rtgt + (size_t)bf * NCH * HW)      + v2;
    const v2f* vp   = (const v2f*)(mvis + (size_t)bf * NS * HW)       + v2;

    // ---- masks/mvis/rtgt: normal (cached) loads — read twice across c-halves ----
    v2f mv[NS], vv[NS];
    #pragma unroll
    for (int s = 0; s < NS; ++s) mv[s] = mp[s * HW2];
    #pragma unroll
    for (int s = 0; s < NS; ++s) vv[s] = vp[s * HW2];

    v2f tv[NCH];
    #pragma unroll
    for (int ch = 0; ch < NCH; ++ch) tv[ch] = tp[ch * HW2];

    // ---- seg/rec: read-once streams -> nontemporal (don't pollute L2) ----
    v2f sv[4];
    #pragma unroll
    for (int c4 = 0; c4 < 4; ++c4)
        sv[c4] = __builtin_nontemporal_load(segp + (c0 + c4) * HW2);

    v2f rr[4][NCH];
    #pragma unroll
    for (int c4 = 0; c4 < 4; ++c4)
        #pragma unroll
        for (int ch = 0; ch < NCH; ++ch)
            rr[c4][ch] = __builtin_nontemporal_load(rp + ((c0 + c4) * NCH + ch) * HW2);

    // ---- Compute ----
    float mb[NS][2], vb[NS][2];
    #pragma unroll
    for (int s = 0; s < NS; ++s) {
        mb[s][0] = (mv[s][0] > 0.5f) ? 1.f : 0.f;
        mb[s][1] = (mv[s][1] > 0.5f) ? 1.f : 0.f;
        vb[s][0] = (vv[s][0] > 0.5f) ? 1.f : 0.f;
        vb[s][1] = (vv[s][1] > 0.5f) ? 1.f : 0.f;
    }

    float acc = 0.f;
    #pragma unroll
    for (int c4 = 0; c4 < 4; ++c4) {
        const int c = c0 + c4;
        const float Ac = A_s[c];
        #pragma unroll
        for (int j = 0; j < 2; ++j) {
            float s  = sv[c4][j];
            float lp = fmaxf(__logf(s), LOG_CLAMP);
            float l1 = fmaxf(__logf(1.0f - s), LOG_CLAMP);
            float d0 = rr[c4][0][j] - tv[0][j];
            float d1 = rr[c4][1][j] - tv[1][j];
            float d2 = rr[c4][2][j] - tv[2][j];
            float D  = d0 * d0 + d1 * d1 + d2 * d2;
            float U = 0.f, V = 0.f;
            #pragma unroll
            for (int s7 = 0; s7 < NS; ++s7) {
                float a = ai_s[s7][c];
                U = fmaf(mb[s7][j], a, U);
                V = fmaf(vb[s7][j], a, V);
            }
            acc += -(Ac * l1 + U * (lp - l1)) * INV_HW + 0.1f * V * D;
        }
    }

    // wave reduce, cross-wave via LDS, one plain store per block (no atomics)
    #pragma unroll
    for (int off = 32; off; off >>= 1) acc += __shfl_down(acc, off, 64);
    __shared__ float wsum[BLOCK / 64];
    const int wid  = tid >> 6;
    const int lane = tid & 63;
    if (lane == 0) wsum[wid] = acc;
    __syncthreads();
    if (tid == 0)
        part[blockIdx.x] = wsum[0] + wsum[1] + wsum[2] + wsum[3];
}

__global__ __launch_bounds__(BLOCK)
void reduce_kernel(const float* __restrict__ part, float* __restrict__ out) {
    const int tid = threadIdx.x;
    float a = 0.f;
    #pragma unroll
    for (int i = 0; i < NPART / BLOCK; ++i)      // 6 each
        a += part[i * BLOCK + tid];
    #pragma unroll
    for (int off = 32; off; off >>= 1) a += __shfl_down(a, off, 64);
    __shared__ float fsum[BLOCK / 64];
    if ((tid & 63) == 0) fsum[tid >> 6] = a;
    __syncthreads();
    if (tid == 0) out[0] = (fsum[0] + fsum[1] + fsum[2] + fsum[3]) * SCALE;
}

extern "C" void kernel_launch(void* const* d_in, const int* in_sizes, int n_in,
                              void* d_out, int out_size, void* d_ws, size_t ws_size,
                              hipStream_t stream) {
    const float* seg   = (const float*)d_in[0];  // (4,6,8,128,128)
    const float* masks = (const float*)d_in[1];  // (4,6,7,128,128)
    const float* rec   = (const float*)d_in[2];  // (4,6,8,3,128,128)
    const float* rtgt  = (const float*)d_in[3];  // (4,6,3,128,128)
    const float* mvis  = (const float*)d_in[4];  // (4,6,7,128,128)
    const float* ai    = (const float*)d_in[5];  // (4,6,7,8)
    float* out  = (float*)d_out;
    float* part = (float*)d_ws;                  // 1536 floats, fully overwritten each call

    em_loss_kernel<<<NPART, BLOCK, 0, stream>>>(seg, masks, rec, rtgt, mvis, ai, part);
    reduce_kernel<<<1, BLOCK, 0, stream>>>(part, out);
}

// Round 14
// 19.628 us; speedup vs baseline: 3.5232x; 1.0393x over previous
//
#include <hip/hip_runtime.h>

// b=4, f=6, n_slots=7, n_buffer=8, h=w=128, 3 channels. bf=24.
constexpr int NB  = 8;
constexpr int NS  = 7;
constexpr int NCH = 3;
constexpr int HW  = 128 * 128;    // 16384
constexpr int HW2 = HW / 2;       // float2 per plane
constexpr int BF  = 24;
constexpr int BLOCK = 256;
constexpr int PXCHUNKS = HW / (BLOCK * 2);       // 32 px-chunks (512 px each)
constexpr int BLOCKS_PER_BF = PXCHUNKS * 2;      // 64 (x2 c-halves)
constexpr int NPART = BF * BLOCKS_PER_BF;        // 1536 blocks / partials
constexpr float INV_HW = 1.0f / (float)HW;
constexpr float SCALE  = 20.0f / (4.0f * 6.0f * 7.0f * 8.0f);
constexpr float LOG_CLAMP = -100.0f;

// Cap 85 VGPR -> 6 waves/SIMD -> 24 waves/CU (grid-saturating). The early
// U/V reduction below keeps the live set ~75-85 so this cap does NOT spill
// (unlike R7, whose 100-reg data set under the same cap exploded to scratch).
__global__ __launch_bounds__(BLOCK, 6)
void em_loss_kernel(const float* __restrict__ seg,
                    const float* __restrict__ masks,
                    const float* __restrict__ rec,
                    const float* __restrict__ rtgt,
                    const float* __restrict__ mvis,
                    const float* __restrict__ ai,
                    float* __restrict__ part) {
    const int bid  = blockIdx.x;
    const int bf   = bid >> 6;                   // / BLOCKS_PER_BF
    const int rem  = bid & 63;
    // bit3 = c-half: blocks sharing a px-chunk are 8 apart -> same XCD under
    // round-robin dispatch -> L2 dedups the shared masks/mvis/rtgt reads.
    const int half  = (rem >> 3) & 1;
    const int chunk = (rem & 7) | ((rem >> 4) << 3);   // 0..31
    const int tid   = threadIdx.x;
    const int v2    = chunk * BLOCK + tid;       // float2 index in plane
    const int c0    = half * 4;

    __shared__ float ai_s[NS][NB];
    __shared__ float A_s[NB];
    if (tid < NS * NB)
        ((float*)ai_s)[tid] = ai[bf * NS * NB + tid];
    __syncthreads();
    if (tid < NB) {
        float a = 0.f;
        #pragma unroll
        for (int s = 0; s < NS; ++s) a += ai_s[s][tid];
        A_s[tid] = a;
    }
    __syncthreads();

    const float2* segp = (const float2*)(seg  + (size_t)bf * NB * HW)       + v2;
    const float2* mp   = (const float2*)(masks + (size_t)bf * NS * HW)      + v2;
    const float2* rp   = (const float2*)(rec  + (size_t)bf * NB * NCH * HW) + v2;
    const float2* tp   = (const float2*)(rtgt + (size_t)bf * NCH * HW)      + v2;
    const float2* vp   = (const float2*)(mvis + (size_t)bf * NS * HW)       + v2;

    // ---- Cluster A: 17 float2 loads (masks, mvis, rtgt) ----
    float2 mv[NS], vv[NS];
    #pragma unroll
    for (int s = 0; s < NS; ++s) mv[s] = mp[s * HW2];
    #pragma unroll
    for (int s = 0; s < NS; ++s) vv[s] = vp[s * HW2];

    float2 tv[NCH];
    #pragma unroll
    for (int ch = 0; ch < NCH; ++ch) tv[ch] = tp[ch * HW2];

    // ---- Early reduction: mv/vv (28 regs) -> U/V (16 regs), then they die ----
    float U[4][2], V[4][2];
    #pragma unroll
    for (int c4 = 0; c4 < 4; ++c4) {
        const int c = c0 + c4;
        float u0 = 0.f, u1 = 0.f, w0 = 0.f, w1 = 0.f;
        #pragma unroll
        for (int s = 0; s < NS; ++s) {
            const float a = ai_s[s][c];
            u0 += (mv[s].x > 0.5f) ? a : 0.f;
            u1 += (mv[s].y > 0.5f) ? a : 0.f;
            w0 += (vv[s].x > 0.5f) ? a : 0.f;
            w1 += (vv[s].y > 0.5f) ? a : 0.f;
        }
        U[c4][0] = u0; U[c4][1] = u1;
        V[c4][0] = w0; V[c4][1] = w1;
    }

    // ---- Cluster B: 16 float2 loads (seg, rec) ----
    float2 sv[4];
    #pragma unroll
    for (int c4 = 0; c4 < 4; ++c4) sv[c4] = segp[(c0 + c4) * HW2];

    float2 rr[4][NCH];
    #pragma unroll
    for (int c4 = 0; c4 < 4; ++c4)
        #pragma unroll
        for (int ch = 0; ch < NCH; ++ch)
            rr[c4][ch] = rp[((c0 + c4) * NCH + ch) * HW2];

    // ---- Final compute ----
    float acc = 0.f;
    #pragma unroll
    for (int c4 = 0; c4 < 4; ++c4) {
        const int c = c0 + c4;
        const float Ac = A_s[c];
        const float* sp  = (const float*)&sv[c4];
        const float* r0p = (const float*)&rr[c4][0];
        const float* r1p = (const float*)&rr[c4][1];
        const float* r2p = (const float*)&rr[c4][2];
        const float* t0p = (const float*)&tv[0];
        const float* t1p = (const float*)&tv[1];
        const float* t2p = (const float*)&tv[2];
        #pragma unroll
        for (int j = 0; j < 2; ++j) {
            float s  = sp[j];
            float lp = fmaxf(__logf(s), LOG_CLAMP);
            float l1 = fmaxf(__logf(1.0f - s), LOG_CLAMP);
            float d0 = r0p[j] - t0p[j];
            float d1 = r1p[j] - t1p[j];
            float d2 = r2p[j] - t2p[j];
            float D  = d0 * d0 + d1 * d1 + d2 * d2;
            acc += -(Ac * l1 + U[c4][j] * (lp - l1)) * INV_HW + 0.1f * V[c4][j] * D;
        }
    }

    // wave reduce, cross-wave via LDS, one plain store per block (no atomics)
    #pragma unroll
    for (int off = 32; off; off >>= 1) acc += __shfl_down(acc, off, 64);
    __shared__ float wsum[BLOCK / 64];
    const int wid  = tid >> 6;
    const int lane = tid & 63;
    if (lane == 0) wsum[wid] = acc;
    __syncthreads();
    if (tid == 0)
        part[blockIdx.x] = wsum[0] + wsum[1] + wsum[2] + wsum[3];
}

__global__ __launch_bounds__(BLOCK)
void reduce_kernel(const float* __restrict__ part, float* __restrict__ out) {
    const int tid = threadIdx.x;
    float a = 0.f;
    #pragma unroll
    for (int i = 0; i < NPART / BLOCK; ++i)      // 6 each
        a += part[i * BLOCK + tid];
    #pragma unroll
    for (int off = 32; off; off >>= 1) a += __shfl_down(a, off, 64);
    __shared__ float fsum[BLOCK / 64];
    if ((tid & 63) == 0) fsum[tid >> 6] = a;
    __syncthreads();
    if (tid == 0) out[0] = (fsum[0] + fsum[1] + fsum[2] + fsum[3]) * SCALE;
}

extern "C" void kernel_launch(void* const* d_in, const int* in_sizes, int n_in,
                              void* d_out, int out_size, void* d_ws, size_t ws_size,
                              hipStream_t stream) {
    const float* seg   = (const float*)d_in[0];  // (4,6,8,128,128)
    const float* masks = (const float*)d_in[1];  // (4,6,7,128,128)
    const float* rec   = (const float*)d_in[2];  // (4,6,8,3,128,128)
    const float* rtgt  = (const float*)d_in[3];  // (4,6,3,128,128)
    const float* mvis  = (const float*)d_in[4];  // (4,6,7,128,128)
    const float* ai    = (const float*)d_in[5];  // (4,6,7,8)
    float* out  = (float*)d_out;
    float* part = (float*)d_ws;                  // 1536 floats, fully overwritten each call

    em_loss_kernel<<<NPART, BLOCK, 0, stream>>>(seg, masks, rec, rtgt, mvis, ai, part);
    reduce_kernel<<<1, BLOCK, 0, stream>>>(part, out);
}